// Round 7
// baseline (90.341 us; speedup 1.0000x reference)
//
#include <hip/hip_runtime.h>
#include <hip/hip_bf16.h>

typedef __attribute__((ext_vector_type(8))) short bf16x8;
typedef __attribute__((ext_vector_type(4))) float f32x4;

#define D_DIM 256   // input feature dim
#define H_DIM 128   // hidden dim per branch
#define NB 128      // row buckets (pow2)
#define B1 256      // edge chunks (pow2)

// RNE float->bf16 (bit pattern)
__device__ inline ushort f2bf(float f) {
    union { float f; unsigned u; } a; a.f = f;
    unsigned r = a.u + 0x7fffu + ((a.u >> 16) & 1u);
    return (ushort)(r >> 16);
}

// K0: build Wt bf16 [hcat][k] from W_nb|W_self (transposed, k-contiguous).
__global__ void k0_init(const float* __restrict__ W_nb, const float* __restrict__ W_self,
                        ushort* __restrict__ Wt) {
    int i = blockIdx.x * 256 + threadIdx.x;
    if (i < 2 * H_DIM * D_DIM) {
        int sel = i >> 15;
        int r   = i & 32767;
        int k   = r >> 7;
        int h   = r & 127;
        const float* W = sel ? W_self : W_nb;
        Wt[(sel * H_DIM + h) * D_DIM + k] = f2bf(W[k * H_DIM + h]);
    }
}

// K1: persistent-B fused GEMM (unchanged from R6).
__global__ __launch_bounds__(512, 2) void k1_gemm(
    const float* __restrict__ x, const ushort* __restrict__ Wt,
    const float* __restrict__ b_nb, const float* __restrict__ b_self,
    const float* __restrict__ W_att,
    float* __restrict__ g_nb, float* __restrict__ g_self, int N, int ntiles)
{
    __shared__ __align__(16) ushort A_lds[64][264];
    __shared__ float part[2][2][64];

    const int t    = threadIdx.x;
    const int lane = t & 63;
    const int w    = t >> 6;
    const int rh   = w >> 2;
    const int cg   = w & 3;
    const int br   = cg >> 1;
    const int ch   = cg & 1;
    const int li   = lane & 15;
    const int grp  = lane >> 4;

    float bias[4], aw[4];
    #pragma unroll
    for (int ni = 0; ni < 4; ni++) {
        int hh = ch * 64 + ni * 16 + li;
        bias[ni] = br ? b_self[hh] : b_nb[hh];
        aw[ni]   = W_att[br * H_DIM + hh];
    }

    bf16x8 Bf[4][8];
    #pragma unroll
    for (int ni = 0; ni < 4; ni++)
        #pragma unroll
        for (int ks = 0; ks < 8; ks++)
            Bf[ni][ks] = *reinterpret_cast<const bf16x8*>(
                Wt + (size_t)(cg * 64 + ni * 16 + li) * D_DIM + ks * 32 + grp * 8);

    const int sr = t >> 3;
    const int sc = t & 7;

    for (int rt = blockIdx.x; rt < ntiles; rt += gridDim.x) {
        const int row0 = rt * 64;

        __syncthreads();
        {
            const int gr = row0 + sr;
            const bool v = gr < N;
            const float4* src = reinterpret_cast<const float4*>(x + (size_t)gr * D_DIM);
            #pragma unroll
            for (int j = 0; j < 8; j++) {
                int c4 = sc + j * 8;
                ushort4 o;
                if (v) {
                    float4 f = src[c4];
                    o.x = f2bf(f.x); o.y = f2bf(f.y); o.z = f2bf(f.z); o.w = f2bf(f.w);
                } else { o.x = 0; o.y = 0; o.z = 0; o.w = 0; }
                *reinterpret_cast<ushort4*>(&A_lds[sr][c4 * 4]) = o;
            }
        }
        __syncthreads();

        f32x4 acc[2][4];
        #pragma unroll
        for (int mi = 0; mi < 2; mi++)
            #pragma unroll
            for (int ni = 0; ni < 4; ni++) acc[mi][ni] = f32x4{0.f, 0.f, 0.f, 0.f};

        #pragma unroll
        for (int ks = 0; ks < 8; ks++) {
            bf16x8 af0 = *reinterpret_cast<const bf16x8*>(&A_lds[rh * 32 + li][ks * 32 + grp * 8]);
            bf16x8 af1 = *reinterpret_cast<const bf16x8*>(&A_lds[rh * 32 + 16 + li][ks * 32 + grp * 8]);
            #pragma unroll
            for (int ni = 0; ni < 4; ni++) {
                acc[0][ni] = __builtin_amdgcn_mfma_f32_16x16x32_bf16(af0, Bf[ni][ks], acc[0][ni], 0, 0, 0);
                acc[1][ni] = __builtin_amdgcn_mfma_f32_16x16x32_bf16(af1, Bf[ni][ks], acc[1][ni], 0, 0, 0);
            }
        }

        float p[2][4];
        #pragma unroll
        for (int mi = 0; mi < 2; mi++)
            #pragma unroll
            for (int r4 = 0; r4 < 4; r4++) p[mi][r4] = 0.f;
        #pragma unroll
        for (int ni = 0; ni < 4; ni++)
            #pragma unroll
            for (int mi = 0; mi < 2; mi++)
                #pragma unroll
                for (int r4 = 0; r4 < 4; r4++) {
                    float y = acc[mi][ni][r4] + bias[ni];
                    y = y > 0.f ? y : 0.f;
                    p[mi][r4] += y * aw[ni];
                }
        #pragma unroll
        for (int mi = 0; mi < 2; mi++)
            #pragma unroll
            for (int r4 = 0; r4 < 4; r4++) {
                float v = p[mi][r4];
                #pragma unroll
                for (int m = 1; m < 16; m <<= 1) v += __shfl_xor(v, m);
                if (li == 0)
                    part[br][ch][rh * 32 + mi * 16 + grp * 4 + r4] = v;
            }
        __syncthreads();

        if (t < 128) {
            int b_ = t >> 6, lr = t & 63;
            int gr = row0 + lr;
            if (gr < N) {
                float val = part[b_][0][lr] + part[b_][1][lr];
                if (b_) g_self[gr] = val; else g_nb[gr] = val;
            }
        }
    }
}

// P1: per-(chunk,bucket) histogram of row>>shift. cnt[b*B1 + chunk].
__global__ __launch_bounds__(256) void p1_count(
    const int* __restrict__ row, unsigned* __restrict__ cnt, int E, int CS, int shift)
{
    __shared__ unsigned c[NB];
    const int t = threadIdx.x;
    for (int i = t; i < NB; i += 256) c[i] = 0;
    __syncthreads();
    int base = blockIdx.x * CS;
    int end  = base + CS; if (end > E) end = E;
    for (int i = base + t; i < end; i += 256)
        atomicAdd(&c[row[i] >> shift], 1u);
    __syncthreads();
    for (int i = t; i < NB; i += 256) cnt[i * B1 + blockIdx.x] = c[i];
}

// P2: single-block exclusive scan of cnt[0..NB*B1) -> off; off[NB*B1] = total.
__global__ __launch_bounds__(1024, 1) void p2_scan(
    const unsigned* __restrict__ cnt, unsigned* __restrict__ off)
{
    __shared__ unsigned tot[1024];
    const int tid = threadIdx.x;
    unsigned loc[32];
    unsigned s = 0;
    const int base = tid * 32;
    #pragma unroll
    for (int j = 0; j < 32; j++) { loc[j] = cnt[base + j]; s += loc[j]; }
    tot[tid] = s;
    __syncthreads();
    for (int d = 1; d < 1024; d <<= 1) {
        unsigned v = (tid >= d) ? tot[tid - d] : 0;
        __syncthreads();
        tot[tid] += v;
        __syncthreads();
    }
    unsigned run = (tid == 0) ? 0 : tot[tid - 1];
    #pragma unroll
    for (int j = 0; j < 32; j++) { off[base + j] = run; run += loc[j]; }
    if (tid == 1023) off[NB * B1] = run;
}

// P3: gate + mask -> out[e]; scatter (row, mv) into bucket-sorted sr/sm via LDS cursors.
// sigmoid(log(u/(1-u)) + la) = u / (u + (1-u)*exp(-la))
__global__ __launch_bounds__(256) void p3_gate_scatter(
    const int* __restrict__ row, const int* __restrict__ col,
    const float* __restrict__ values, const float* __restrict__ noise,
    const float* __restrict__ g_nb, const float* __restrict__ g_self,
    const float* __restrict__ b_att, const unsigned* __restrict__ off,
    float* __restrict__ out, int* __restrict__ srow, float* __restrict__ smv,
    int E, int CS, int shift)
{
    __shared__ unsigned cur[NB];
    const int t = threadIdx.x;
    for (int i = t; i < NB; i += 256) cur[i] = off[i * B1 + blockIdx.x];
    __syncthreads();
    const float ba = b_att[0];
    int base = blockIdx.x * CS;
    int end  = base + CS; if (end > E) end = E;
    for (int e = base + t; e < end; e += 256) {
        int   r = row[e], c = col[e];
        float v = values[e];
        float u = noise[e] + 1e-7f;
        float la = g_nb[r] + g_self[c] + ba;
        float gate = u / (u + (1.f - u) * __expf(-la));
        float mask = fminf(fmaxf(gate * 1.6f - 0.5f, 0.f), 1.f);
        float m = v * mask;
        out[e] = m;
        unsigned p = atomicAdd(&cur[r >> shift], 1u);
        srow[p] = r; smv[p] = m;
    }
}

// P4: one block per bucket — LDS row accumulator, then dis[n]=rsqrt(1e-10+sum).
__global__ __launch_bounds__(1024, 1) void p4_reduce(
    const int* __restrict__ srow, const float* __restrict__ smv,
    const unsigned* __restrict__ off, float* __restrict__ dis,
    int N, int shift)
{
    __shared__ float acc[4096];
    const int b = blockIdx.x, t = threadIdx.x;
    const int NR = 1 << shift;
    for (int i = t; i < NR; i += 1024) acc[i] = 0.f;
    __syncthreads();
    unsigned s = off[b * B1];
    unsigned e = off[(b + 1) * B1];
    const int lo = b << shift;
    for (unsigned i = s + t; i < e; i += 1024)
        atomicAdd(&acc[srow[i] - lo], smv[i]);
    __syncthreads();
    for (int i = t; i < NR; i += 1024) {
        int n = lo + i;
        if (n < N) dis[n] = rsqrtf(1e-10f + acc[i]);
    }
}

// K3: symmetric degree normalization, gathers precomputed dis.
__global__ __launch_bounds__(256) void k3_edge2(
    const int* __restrict__ row, const int* __restrict__ col,
    float* __restrict__ out, const float* __restrict__ dis, int E)
{
    int e = blockIdx.x * 256 + threadIdx.x;
    if (e >= E) return;
    out[e] = out[e] * dis[row[e]] * dis[col[e]];
}

extern "C" void kernel_launch(void* const* d_in, const int* in_sizes, int n_in,
                              void* d_out, int out_size, void* d_ws, size_t ws_size,
                              hipStream_t stream) {
    const float* x      = (const float*)d_in[0];
    const float* W_nb   = (const float*)d_in[1];
    const float* b_nb   = (const float*)d_in[2];
    const float* W_self = (const float*)d_in[3];
    const float* b_self = (const float*)d_in[4];
    const float* W_att  = (const float*)d_in[5];
    const float* b_att  = (const float*)d_in[6];
    const float* values = (const float*)d_in[7];
    const float* noise  = (const float*)d_in[8];
    const int*   row    = (const int*)d_in[9];
    const int*   col    = (const int*)d_in[10];

    const int N = in_sizes[0] / D_DIM;
    const int E = in_sizes[7];
    float* out = (float*)d_out;

    // bucket shift: smallest s with (N-1)>>s < NB  (N=50000 -> 9, NR=512)
    int shift = 0;
    while (((N - 1) >> shift) >= NB) shift++;
    if (shift > 12) shift = 12;  // LDS acc cap (4096 rows); N<=NB*4096 always here

    char* ws = (char*)d_ws;
    ushort*   Wt     = (ushort*)ws;                     // 131072 B
    float*    g_nb   = (float*)(ws + 131072);           // N
    float*    g_self = g_nb + N;                        // N
    float*    dis    = g_self + N;                      // N
    unsigned* cnt    = (unsigned*)(dis + N);            // NB*B1
    unsigned* off    = cnt + NB * B1;                   // NB*B1 + 1
    int*      srow   = (int*)(off + NB * B1 + 1);       // E
    float*    smv    = (float*)(srow + E);              // E

    k0_init<<<(2 * H_DIM * D_DIM + 255) / 256, 256, 0, stream>>>(W_nb, W_self, Wt);

    const int ntiles = (N + 63) / 64;
    k1_gemm<<<256, 512, 0, stream>>>(x, Wt, b_nb, b_self, W_att, g_nb, g_self, N, ntiles);

    const int CS = (E + B1 - 1) / B1;
    p1_count<<<B1, 256, 0, stream>>>(row, cnt, E, CS, shift);
    p2_scan<<<1, 1024, 0, stream>>>(cnt, off);
    p3_gate_scatter<<<B1, 256, 0, stream>>>(row, col, values, noise, g_nb, g_self,
                                            b_att, off, out, srow, smv, E, CS, shift);
    p4_reduce<<<NB, 1024, 0, stream>>>(srow, smv, off, dis, N, shift);

    k3_edge2<<<(E + 255) / 256, 256, 0, stream>>>(row, col, out, dis, E);
}